// Round 10
// baseline (299.686 us; speedup 1.0000x reference)
//
#include <hip/hip_runtime.h>

#define SEQ   2048
#define NHEAD 16
#define DKK   64
#define HID   1024

typedef __attribute__((ext_vector_type(8))) short bf16x8;
typedef __attribute__((ext_vector_type(4))) float f32x4;

__device__ __forceinline__ unsigned short f32_bf16(float f) {
    unsigned int u = __builtin_bit_cast(unsigned int, f);
    u += 0x7fffu + ((u >> 16) & 1u);
    return (unsigned short)(u >> 16);
}

// one-instruction packed f32x2 -> bf16x2 (RNE), per T12 recipe
__device__ __forceinline__ unsigned int cvt_pk_bf16(float lo, float hi) {
    unsigned int r;
    asm("v_cvt_pk_bf16_f32 %0, %1, %2" : "=v"(r) : "v"(lo), "v"(hi));
    return r;
}

// raw v_exp_f32 (2^x). Scores bounded (|x| < ~45), no range reduction needed.
__device__ __forceinline__ float fast_exp2(float x) {
    float r;
    asm("v_exp_f32 %0, %1" : "=v"(r) : "v"(x));
    return r;
}

// async global->LDS 16B copy (DMA, no VGPR round-trip)
__device__ __forceinline__ void glds16(const void* g, void* l) {
    __builtin_amdgcn_global_load_lds(
        (const __attribute__((address_space(1))) unsigned int*)g,
        (__attribute__((address_space(3))) unsigned int*)l, 16, 0, 0);
}

// ---------------------------------------------------------------------------
// Kernel A: fused prep — fp32->bf16 convert of all 7 tensors + mask bit-pack
// (R4-verified int4 mask form; ballot variant measured slower).
// ---------------------------------------------------------------------------
__global__ __launch_bounds__(256)
void prep_kernel(const float* __restrict__ q, const float* __restrict__ k,
                 const float* __restrict__ v,
                 const float* __restrict__ Wq, const float* __restrict__ Wk,
                 const float* __restrict__ Wv, const float* __restrict__ Wo,
                 const int* __restrict__ mask,
                 unsigned short* __restrict__ ws, unsigned long long* __restrict__ Mb)
{
    const int bid = blockIdx.x;
    if (bid < 16384) {
        int i = bid * 256 + threadIdx.x;            // float4 index
        const float* src; int off;
        if (i < 1048576)      { src = q;  off = i; }
        else if (i < 2097152) { src = k;  off = i - 1048576; }
        else if (i < 3145728) { src = v;  off = i - 2097152; }
        else if (i < 3407872) { src = Wq; off = i - 3145728; }
        else if (i < 3670016) { src = Wk; off = i - 3407872; }
        else if (i < 3932160) { src = Wv; off = i - 3670016; }
        else                  { src = Wo; off = i - 3932160; }
        float4 a = ((const float4*)src)[off];
        ((uint2*)ws)[i] = make_uint2(cvt_pk_bf16(a.x, a.y), cvt_pk_bf16(a.z, a.w));
    } else {
        int idx = (bid - 16384) * 256 + threadIdx.x;
        const int* src = mask + (size_t)idx * 64;
        unsigned long long wv = 0;
        #pragma unroll
        for (int i = 0; i < 16; ++i) {
            int4 m4 = *(const int4*)(src + i * 4);
            wv |= (unsigned long long)(m4.x != 0) << (i * 4 + 0);
            wv |= (unsigned long long)(m4.y != 0) << (i * 4 + 1);
            wv |= (unsigned long long)(m4.z != 0) << (i * 4 + 2);
            wv |= (unsigned long long)(m4.w != 0) << (i * 4 + 3);
        }
        Mb[idx] = wv;
    }
}

// ---------------------------------------------------------------------------
// Kernel 1: QKV projections (R9-verified: double-buffer loop, (256,3) bound,
// fused V-transpose epilogue writing Vt[b,h,d,s] coalesced).
// ---------------------------------------------------------------------------
__global__ __launch_bounds__(256, 3)
void proj_kernel(const unsigned short* __restrict__ xq, const unsigned short* __restrict__ xk,
                 const unsigned short* __restrict__ xv,
                 const unsigned short* __restrict__ Wqb, const unsigned short* __restrict__ Wkb,
                 const unsigned short* __restrict__ Wvb,
                 const float* __restrict__ bq_, const float* __restrict__ bk_,
                 const float* __restrict__ bv_,
                 unsigned short* __restrict__ Qh, unsigned short* __restrict__ Kh,
                 unsigned short* __restrict__ Vt)
{
    const int z = blockIdx.z;
    const unsigned short* X; const unsigned short* W; const float* bias;
    if (z == 0)      { X = xq; W = Wqb; bias = bq_; }
    else if (z == 1) { X = xk; W = Wkb; bias = bk_; }
    else             { X = xv; W = Wvb; bias = bv_; }

    const int m0 = blockIdx.x * 128;
    const int n0 = blockIdx.y * 128;
    const int tid  = threadIdx.x;
    const int lane = tid & 63, wid = tid >> 6;
    const int wm = (wid >> 1) * 64, wn = (wid & 1) * 64;
    const int l15 = lane & 15, quad = lane >> 4;

    // unified 32 KB: As = SH[0..8191] (2 bufs x 4096), Bs = SH[8192..16383];
    // reused as the 128x128 ushort transpose tile T after the K-loop (z=2).
    __shared__ __align__(16) unsigned short SH[16384];
    unsigned short* As = SH;
    unsigned short* Bs = SH + 8192;

    const int r0 = tid >> 2, cg = tid & 3;
    const unsigned short* gA = X + (size_t)(m0 + r0) * HID + ((cg ^ (r0 & 3)) * 8);
    const unsigned short* gB = W + (size_t)(n0 + r0) * HID + ((cg ^ (r0 & 3)) * 8);

    const int cgsel = (quad ^ (l15 & 3)) * 8;

    f32x4 acc[4][4];
    #pragma unroll
    for (int i = 0; i < 4; ++i)
        #pragma unroll
        for (int j = 0; j < 4; ++j)
            acc[i][j] = f32x4{0.f, 0.f, 0.f, 0.f};

    // prologue: stage k0=0 into buf 0
    glds16(gA, &As[tid * 8]);
    glds16(gA + (size_t)64 * HID, &As[(tid + 256) * 8]);
    glds16(gB, &Bs[tid * 8]);
    glds16(gB + (size_t)64 * HID, &Bs[(tid + 256) * 8]);
    __syncthreads();

    for (int k0 = 0; k0 < HID; k0 += 32) {
        const int cur = ((k0 >> 5) & 1) * 4096;
        if (k0 + 32 < HID) {                       // prefetch next K-step
            const int nb = (((k0 >> 5) & 1) ^ 1) * 4096;
            glds16(gA + k0 + 32, &As[nb + tid * 8]);
            glds16(gA + (size_t)64 * HID + k0 + 32, &As[nb + (tid + 256) * 8]);
            glds16(gB + k0 + 32, &Bs[nb + tid * 8]);
            glds16(gB + (size_t)64 * HID + k0 + 32, &Bs[nb + (tid + 256) * 8]);
        }

        bf16x8 af[4], bfr[4];
        #pragma unroll
        for (int mi = 0; mi < 4; ++mi)
            af[mi] = *(const bf16x8*)&As[cur + (wm + mi * 16 + l15) * 32 + cgsel];
        #pragma unroll
        for (int ni = 0; ni < 4; ++ni)
            bfr[ni] = *(const bf16x8*)&Bs[cur + (wn + ni * 16 + l15) * 32 + cgsel];
        __builtin_amdgcn_s_setprio(1);
        #pragma unroll
        for (int mi = 0; mi < 4; ++mi)
            #pragma unroll
            for (int ni = 0; ni < 4; ++ni)
                acc[mi][ni] = __builtin_amdgcn_mfma_f32_16x16x32_bf16(
                    af[mi], bfr[ni], acc[mi][ni], 0, 0, 0);
        __builtin_amdgcn_s_setprio(0);
        __syncthreads();                           // reads done + prefetch drained
    }

    if (z == 2) {
        // ---- fused V transpose: acc -> T (swizzled) -> Vt[d][s] coalesced --
        #pragma unroll
        for (int mi = 0; mi < 4; ++mi) {
            #pragma unroll
            for (int ni = 0; ni < 4; ++ni) {
                int ncol = wn + ni * 16 + l15;
                float bv = bias[n0 + ncol];
                #pragma unroll
                for (int r = 0; r < 4; ++r) {
                    int row = wm + mi * 16 + quad * 4 + r;
                    SH[row * 128 + (((ncol >> 3) ^ (row & 15)) * 8) + (ncol & 7)] =
                        f32_bf16(acc[mi][ni][r] + bv);
                }
            }
        }
        __syncthreads();
        const int bb = m0 >> 11, sg0 = m0 & 2047;
        #pragma unroll
        for (int jj = 0; jj < 8; ++jj) {
            int idx = tid + jj * 256;
            int colr = idx >> 4, ch = idx & 15;
            int n = n0 + colr, hh = n >> 6, d = n & 63;
            unsigned short v8[8];
            #pragma unroll
            for (int e = 0; e < 8; ++e) {
                int s = ch * 8 + e;
                v8[e] = SH[s * 128 + (((colr >> 3) ^ (s & 15)) * 8) + (colr & 7)];
            }
            uint4 ov;
            ov.x = (unsigned)v8[0] | ((unsigned)v8[1] << 16);
            ov.y = (unsigned)v8[2] | ((unsigned)v8[3] << 16);
            ov.z = (unsigned)v8[4] | ((unsigned)v8[5] << 16);
            ov.w = (unsigned)v8[6] | ((unsigned)v8[7] << 16);
            *(uint4*)(Vt + (((size_t)(bb * NHEAD + hh) * DKK + d) * SEQ + sg0 + ch * 8)) = ov;
        }
        return;
    }

    const float QSCALE = 0.18033688f;   // 0.125 * log2(e)
    #pragma unroll
    for (int mi = 0; mi < 4; ++mi) {
        #pragma unroll
        for (int ni = 0; ni < 4; ++ni) {
            int n = n0 + wn + ni * 16 + l15;
            float bv = bias[n];
            int hh = n >> 6, d = n & 63;
            #pragma unroll
            for (int r = 0; r < 4; ++r) {
                int m = m0 + wm + mi * 16 + quad * 4 + r;
                int bb = m >> 11, s = m & 2047;
                float val = acc[mi][ni][r] + bv;
                if (z == 0)
                    Qh[((size_t)(bb * NHEAD + hh) * SEQ + s) * DKK + d] = f32_bf16(val * QSCALE);
                else
                    Kh[((size_t)(bb * NHEAD + hh) * SEQ + s) * DKK + d] = f32_bf16(val);
            }
        }
    }
}

// ---------------------------------------------------------------------------
// Kernel 2: flash attention.  R8 datapath (swapped-QK^T, counted vmcnt,
// XCD remap) with 8-WAVE BLOCKS (512 threads, QBLK=128):
//  - each wave still owns 16 q-rows (per-wave code identical, VGPR 52);
//  - K/V tile staging shared by 8 waves (was 4): CU staging traffic/tile
//    64->48 KB, per-thread vm ops 5->3;
//  - LDS 48 KB -> 3 blocks/CU = 24 waves/CU (was 16): 6 waves/SIMD hiding.
// ---------------------------------------------------------------------------
__global__ __launch_bounds__(512, 6)
void attn_kernel(const unsigned short* __restrict__ Qh, const unsigned short* __restrict__ Kh,
                 const unsigned short* __restrict__ Vt,
                 const unsigned long long* __restrict__ Mb,
                 unsigned short* __restrict__ Om)
{
    // XCD-aware decode: flat%8 = XCD; all 16 q-tiles of one (b,h) on one XCD
    const int flat = blockIdx.x;           // 0..511
    const int xcd  = flat & 7;
    const int rest = flat >> 3;            // 0..63
    const int qt   = rest & 15;
    const int g    = rest >> 4;            // 0..3
    const int hb   = g * 8 + xcd;          // 0..31
    const int h    = hb & 15;
    const int b    = hb >> 4;

    const int tid  = threadIdx.x;
    const int lane = tid & 63, w = tid >> 6;        // w = 0..7
    const int l15 = lane & 15, quad = lane >> 4;
    const int q0 = qt * 128;

    const size_t hoff = (size_t)(b * NHEAD + h) * SEQ * DKK;
    const unsigned short* Qp = Qh + hoff;
    const unsigned short* Kp = Kh + hoff;
    const unsigned short* Vp = Vt + hoff;   // [d][s]

    __shared__ __align__(16) unsigned short Ks[2][64 * 64];   // 16 KB
    __shared__ __align__(16) unsigned short Vs[2][64 * 64];   // 16 KB
    __shared__ __align__(16) unsigned short Ps[8][16 * 64];   // 16 KB

    // staging: one 16B chunk per thread per tensor: row = tid>>3, sub = tid&7
    const int sr0 = tid >> 3, ss0 = tid & 7;
    const unsigned short* Kg0 = Kp + sr0 * DKK + ((ss0 ^ (sr0 & 7)) * 8);
    const unsigned short* Vg0 = Vp + (size_t)sr0 * SEQ + ((ss0 ^ (sr0 & 7)) * 8);

    const int swz0 = ((0 * 4 + quad) ^ (l15 & 7)) * 8;
    const int swz1 = ((1 * 4 + quad) ^ (l15 & 7)) * 8;

    const int xsw = l15 & 14;
    int wadr[4];
    #pragma unroll
    for (int ni = 0; ni < 4; ++ni)
        wadr[ni] = l15 * 64 + (((ni * 4 + quad) ^ xsw) * 4);
    const int padr0 = l15 * 64 + (((quad * 2) ^ xsw) * 4);
    const int padr1 = l15 * 64 + (((8 + quad * 2) ^ xsw) * 4);

    // prologue: issue tile 0 (2 DMA/thread); Q frags + mask ride same queue
    glds16(Kg0, &Ks[0][tid * 8]);
    glds16(Vg0, &Vs[0][tid * 8]);

    bf16x8 qf[2];
    #pragma unroll
    for (int kc = 0; kc < 2; ++kc)
        qf[kc] = *(const bf16x8*)(Qp + (size_t)(q0 + w * 16 + l15) * DKK + kc * 32 + quad * 8);

    bf16x8 onesf;
    #pragma unroll
    for (int i = 0; i < 8; ++i) onesf[i] = (short)0x3F80;

    f32x4 o_acc[4];
    f32x4 l_acc = f32x4{0.f, 0.f, 0.f, 0.f};
    #pragma unroll
    for (int nd = 0; nd < 4; ++nd) o_acc[nd] = f32x4{0.f, 0.f, 0.f, 0.f};

    const unsigned long long* Mrow =
        Mb + ((size_t)b * SEQ + q0 + w * 16 + l15) * (SEQ / 64);
    unsigned long long mw_cur = Mrow[0];

    for (int kt = 0; kt < SEQ / 64; ++kt) {
        const int cur = kt & 1;
        unsigned long long mw_nxt = 0ull;

        // --- A: issue next batch (exactly 3 vm ops/thread when taken) -----
        if (kt < SEQ / 64 - 1) {
            const int nb = cur ^ 1;
            glds16(Kg0 + (kt + 1) * 64 * DKK, &Ks[nb][tid * 8]);
            glds16(Vg0 + (kt + 1) * 64,       &Vs[nb][tid * 8]);
            mw_nxt = Mrow[kt + 1];
            // --- B: wait only batch kt (all but the 3 newest), then join --
            asm volatile("s_waitcnt vmcnt(3)" ::: "memory");
        } else {
            asm volatile("s_waitcnt vmcnt(0)" ::: "memory");
        }
        __builtin_amdgcn_s_barrier();          // batch kt resident for ALL waves
        __builtin_amdgcn_sched_barrier(0);     // keep C below the barrier

        // --- C: compute on tile kt ----------------------------------------
        const unsigned long long mwq = mw_cur >> (quad * 4);

        f32x4 st[4];
        #pragma unroll
        for (int ni = 0; ni < 4; ++ni) st[ni] = f32x4{0.f, 0.f, 0.f, 0.f};
        {
            bf16x8 kb[4];
            #pragma unroll
            for (int ni = 0; ni < 4; ++ni)
                kb[ni] = *(const bf16x8*)&Ks[cur][(ni * 16 + l15) * 64 + swz0];
            __builtin_amdgcn_s_setprio(1);
            #pragma unroll
            for (int ni = 0; ni < 4; ++ni)
                st[ni] = __builtin_amdgcn_mfma_f32_16x16x32_bf16(kb[ni], qf[0], st[ni], 0, 0, 0);
            __builtin_amdgcn_s_setprio(0);
            #pragma unroll
            for (int ni = 0; ni < 4; ++ni)
                kb[ni] = *(const bf16x8*)&Ks[cur][(ni * 16 + l15) * 64 + swz1];
            __builtin_amdgcn_s_setprio(1);
            #pragma unroll
            for (int ni = 0; ni < 4; ++ni)
                st[ni] = __builtin_amdgcn_mfma_f32_16x16x32_bf16(kb[ni], qf[1], st[ni], 0, 0, 0);
            __builtin_amdgcn_s_setprio(0);
        }

        // softmax numerator -> P (bf16), packed via v_cvt_pk_bf16_f32
        #pragma unroll
        for (int ni = 0; ni < 4; ++ni) {
            const unsigned int b4 = (unsigned int)(mwq >> (ni * 16)) & 0xFu;
            float p0 = (b4 & 1u) ? fast_exp2(st[ni][0]) : 1.0f;
            float p1 = (b4 & 2u) ? fast_exp2(st[ni][1]) : 1.0f;
            float p2 = (b4 & 4u) ? fast_exp2(st[ni][2]) : 1.0f;
            float p3 = (b4 & 8u) ? fast_exp2(st[ni][3]) : 1.0f;
            *(uint2*)&Ps[w][wadr[ni]] = make_uint2(cvt_pk_bf16(p0, p1), cvt_pk_bf16(p2, p3));
        }

        // PV + row-sum (ones trick)
        {
            bf16x8 pa = *(const bf16x8*)&Ps[w][padr0];
            bf16x8 vb[4];
            #pragma unroll
            for (int nd = 0; nd < 4; ++nd)
                vb[nd] = *(const bf16x8*)&Vs[cur][(nd * 16 + l15) * 64 + swz0];
            __builtin_amdgcn_s_setprio(1);
            l_acc = __builtin_amdgcn_mfma_f32_16x16x32_bf16(pa, onesf, l_acc, 0, 0, 0);
            #pragma unroll
            for (int nd = 0; nd < 4; ++nd)
                o_acc[nd] = __builtin_amdgcn_mfma_f32_16x16x32_bf16(pa, vb[nd], o_acc[nd], 0, 0, 0);
            __builtin_amdgcn_s_setprio(0);

            pa = *(const bf16x8*)&Ps[w][padr1];
            #pragma unroll
            for (int nd = 0; nd < 4; ++nd)
                vb[nd] = *(const bf16x8*)&Vs[cur][(nd * 16 + l15) * 64 + swz1];
            __builtin_amdgcn_s_setprio(1);
            l_acc = __builtin_amdgcn_mfma_f32_16x16x32_bf16(pa, onesf, l_acc, 0, 0, 0);
            #pragma unroll
            for (int nd = 0; nd < 4; ++nd)
                o_acc[nd] = __builtin_amdgcn_mfma_f32_16x16x32_bf16(pa, vb[nd], o_acc[nd], 0, 0, 0);
            __builtin_amdgcn_s_setprio(0);
        }

        mw_cur = mw_nxt;

        // --- D: all reads of buf[cur] done before next A overwrites it ----
        __builtin_amdgcn_s_barrier();
        __builtin_amdgcn_sched_barrier(0);     // pin next A below this barrier
    }

    #pragma unroll
    for (int r = 0; r < 4; ++r) {
        float rinv = 1.0f / l_acc[r];
        int row = q0 + w * 16 + quad * 4 + r;
        #pragma unroll
        for (int nd = 0; nd < 4; ++nd)
            Om[((size_t)b * SEQ + row) * HID + h * DKK + nd * 16 + l15] =
                f32_bf16(o_acc[nd][r] * rinv);
    }
}

// ---------------------------------------------------------------------------
// Kernel 3: out = Om @ Wo^T + bo (fp32 out).  128x64 tiles, R4-verified
// double-buffer single-barrier K-loop.
// ---------------------------------------------------------------------------
__global__ __launch_bounds__(256, 2)
void outproj_kernel(const unsigned short* __restrict__ Om, const unsigned short* __restrict__ Wob,
                    const float* __restrict__ bo_, float* __restrict__ out)
{
    const int m0 = blockIdx.x * 128;
    const int n0 = blockIdx.y * 64;
    const int tid  = threadIdx.x;
    const int lane = tid & 63, wid = tid >> 6;
    const int wm = (wid >> 1) * 64, wn = (wid & 1) * 32;
    const int l15 = lane & 15, quad = lane >> 4;

    __shared__ __align__(16) unsigned short As[2][128 * 32];   // 2 x 8 KB
    __shared__ __align__(16) unsigned short Bs[2][64 * 32];    // 2 x 4 KB

    const int r0 = tid >> 2, cg = tid & 3;
    const unsigned short* gA = Om + (size_t)(m0 + r0) * HID + ((cg ^ (r0 & 3)) * 8);
    const unsigned short* gB = Wob + (size_t)(n0 + r0) * HID + ((cg ^ (r0 & 3)) * 8);
    const int cgsel = (quad ^ (l15 & 3)) * 8;

    f32x4 acc[4][2];
    #pragma unroll
    for (int i = 0; i < 4; ++i)
        #pragma unroll
        for (int j = 0; j < 2; ++j)
            acc[i][j] = f32x4{0.f, 0.f, 0.f, 0.f};

    // prologue: stage k0=0
    glds16(gA, &As[0][tid * 8]);
    glds16(gA + (size_t)64 * HID, &As[0][(tid + 256) * 8]);
    glds16(gB, &Bs[0][tid * 8]);
    __syncthreads();

    for (int k0 = 0; k0 < HID; k0 += 32) {
        const int cur = (k0 >> 5) & 1;
        if (k0 + 32 < HID) {
            const int nb = cur ^ 1;
            glds16(gA + k0 + 32, &As[nb][tid * 8]);
            glds16(gA + (size_t)64 * HID + k0 + 32, &As[nb][(tid + 256) * 8]);
            glds16(gB + k0 + 32, &Bs[nb][tid * 8]);
        }

        bf16x8 af[4], bfr[2];
        #pragma unroll
        for (int mi = 0; mi < 4; ++mi)
            af[mi] = *(const bf16x8*)&As[cur][(wm + mi * 16 + l15) * 32 + cgsel];
        #pragma unroll
        for (int ni = 0; ni < 2; ++ni)
            bfr[ni] = *(const bf16x8*)&Bs[cur][(wn + ni * 16 + l15) * 32 + cgsel];
        __builtin_amdgcn_s_setprio(1);
        #pragma unroll
        for (int mi = 0; mi < 4; ++mi)
            #pragma unroll
            for (int ni = 0; ni < 2; ++ni)
                acc[mi][ni] = __builtin_amdgcn_mfma_f32_16x16x32_bf16(
                    af[mi], bfr[ni], acc[mi][ni], 0, 0, 0);
        __builtin_amdgcn_s_setprio(0);
        __syncthreads();
    }

    #pragma unroll
    for (int mi = 0; mi < 4; ++mi) {
        #pragma unroll
        for (int ni = 0; ni < 2; ++ni) {
            int n = n0 + wn + ni * 16 + l15;
            float bv = bo_[n];
            #pragma unroll
            for (int r = 0; r < 4; ++r) {
                int m = m0 + wm + mi * 16 + quad * 4 + r;
                out[(size_t)m * HID + n] = acc[mi][ni][r] + bv;
            }
        }
    }
}

// ---------------------------------------------------------------------------
extern "C" void kernel_launch(void* const* d_in, const int* in_sizes, int n_in,
                              void* d_out, int out_size, void* d_ws, size_t ws_size,
                              hipStream_t stream) {
    const float* q    = (const float*)d_in[0];
    const float* k    = (const float*)d_in[1];
    const float* v    = (const float*)d_in[2];
    const int*   mask = (const int*)  d_in[3];
    const float* Wq   = (const float*)d_in[4];
    const float* bq   = (const float*)d_in[5];
    const float* Wk   = (const float*)d_in[6];
    const float* bk   = (const float*)d_in[7];
    const float* Wv   = (const float*)d_in[8];
    const float* bv   = (const float*)d_in[9];
    const float* Wo   = (const float*)d_in[10];
    const float* bo   = (const float*)d_in[11];
    float* out = (float*)d_out;

    // workspace layout (bf16 element offsets):
    unsigned short* ws  = (unsigned short*)d_ws;
    unsigned short* qb  = ws;                  // 4194304 elems (B*S*H)
    unsigned short* kbx = ws + 4194304;
    unsigned short* vbx = ws + 8388608;
    unsigned short* Wqb = ws + 12582912;       // 1048576 elems each
    unsigned short* Wkb = ws + 13631488;
    unsigned short* Wvb = ws + 14680064;
    unsigned short* Wob = ws + 15728640;
    unsigned short* Qh  = ws + 16777216;
    unsigned short* Kh  = ws + 20971520;
    unsigned short* Vt  = ws + 25165824;
    unsigned short* Om  = ws;                  // alias qb (dead after proj)
    unsigned long long* Mb = (unsigned long long*)(ws + 29360128);  // 1 MB

    prep_kernel<<<dim3(16896), 256, 0, stream>>>(q, k, v, Wq, Wk, Wv, Wo, mask, ws, Mb);

    proj_kernel<<<dim3(32, 8, 3), 256, 0, stream>>>(qb, kbx, vbx, Wqb, Wkb, Wvb,
                                                    bq, bk, bv, Qh, Kh, Vt);
    attn_kernel<<<dim3(512), 512, 0, stream>>>(Qh, Kh, Vt, Mb, Om);
    outproj_kernel<<<dim3(32, 16), 256, 0, stream>>>(Om, Wob, bo, out);
}

// Round 11
// 273.712 us; speedup vs baseline: 1.0949x; 1.0949x over previous
//
#include <hip/hip_runtime.h>

#define SEQ   2048
#define NHEAD 16
#define DKK   64
#define HID   1024

typedef __attribute__((ext_vector_type(8))) short bf16x8;
typedef __attribute__((ext_vector_type(4))) float f32x4;

__device__ __forceinline__ unsigned short f32_bf16(float f) {
    unsigned int u = __builtin_bit_cast(unsigned int, f);
    u += 0x7fffu + ((u >> 16) & 1u);
    return (unsigned short)(u >> 16);
}

// one-instruction packed f32x2 -> bf16x2 (RNE), per T12 recipe
__device__ __forceinline__ unsigned int cvt_pk_bf16(float lo, float hi) {
    unsigned int r;
    asm("v_cvt_pk_bf16_f32 %0, %1, %2" : "=v"(r) : "v"(lo), "v"(hi));
    return r;
}

// raw v_exp_f32 (2^x). Scores bounded (|x| < ~45), no range reduction needed.
__device__ __forceinline__ float fast_exp2(float x) {
    float r;
    asm("v_exp_f32 %0, %1" : "=v"(r) : "v"(x));
    return r;
}

// half-exchange between two VGPRs: after call, a = [a.lo | b.lo], b = [a.hi | b.hi]
// (v_permlane32_swap_b32 swaps vdst's upper 32 lanes with vsrc's lower 32 lanes)
__device__ __forceinline__ void plane32_swap(unsigned int& a, unsigned int& b) {
    asm volatile("v_permlane32_swap_b32 %0, %1" : "+v"(a), "+v"(b));
}

// lane ^= 16 within each 32-lane half (BitMode xor=16: documented 0x401F pattern)
__device__ __forceinline__ unsigned int swz16(unsigned int v) {
    return (unsigned int)__builtin_amdgcn_ds_swizzle((int)v, 0x401F);
}

// async global->LDS 16B copy (DMA, no VGPR round-trip)
__device__ __forceinline__ void glds16(const void* g, void* l) {
    __builtin_amdgcn_global_load_lds(
        (const __attribute__((address_space(1))) unsigned int*)g,
        (__attribute__((address_space(3))) unsigned int*)l, 16, 0, 0);
}

// ---------------------------------------------------------------------------
// Kernel A: fused prep — fp32->bf16 convert of all 7 tensors + mask bit-pack
// (R4-verified int4 mask form; ballot variant measured slower).
// ---------------------------------------------------------------------------
__global__ __launch_bounds__(256)
void prep_kernel(const float* __restrict__ q, const float* __restrict__ k,
                 const float* __restrict__ v,
                 const float* __restrict__ Wq, const float* __restrict__ Wk,
                 const float* __restrict__ Wv, const float* __restrict__ Wo,
                 const int* __restrict__ mask,
                 unsigned short* __restrict__ ws, unsigned long long* __restrict__ Mb)
{
    const int bid = blockIdx.x;
    if (bid < 16384) {
        int i = bid * 256 + threadIdx.x;            // float4 index
        const float* src; int off;
        if (i < 1048576)      { src = q;  off = i; }
        else if (i < 2097152) { src = k;  off = i - 1048576; }
        else if (i < 3145728) { src = v;  off = i - 2097152; }
        else if (i < 3407872) { src = Wq; off = i - 3145728; }
        else if (i < 3670016) { src = Wk; off = i - 3407872; }
        else if (i < 3932160) { src = Wv; off = i - 3670016; }
        else                  { src = Wo; off = i - 3932160; }
        float4 a = ((const float4*)src)[off];
        ((uint2*)ws)[i] = make_uint2(cvt_pk_bf16(a.x, a.y), cvt_pk_bf16(a.z, a.w));
    } else {
        int idx = (bid - 16384) * 256 + threadIdx.x;
        const int* src = mask + (size_t)idx * 64;
        unsigned long long wv = 0;
        #pragma unroll
        for (int i = 0; i < 16; ++i) {
            int4 m4 = *(const int4*)(src + i * 4);
            wv |= (unsigned long long)(m4.x != 0) << (i * 4 + 0);
            wv |= (unsigned long long)(m4.y != 0) << (i * 4 + 1);
            wv |= (unsigned long long)(m4.z != 0) << (i * 4 + 2);
            wv |= (unsigned long long)(m4.w != 0) << (i * 4 + 3);
        }
        Mb[idx] = wv;
    }
}

// ---------------------------------------------------------------------------
// Kernel 1: QKV projections (R9-verified: double-buffer loop, (256,3) bound,
// fused V-transpose epilogue writing Vt[b,h,d,s] coalesced).
// ---------------------------------------------------------------------------
__global__ __launch_bounds__(256, 3)
void proj_kernel(const unsigned short* __restrict__ xq, const unsigned short* __restrict__ xk,
                 const unsigned short* __restrict__ xv,
                 const unsigned short* __restrict__ Wqb, const unsigned short* __restrict__ Wkb,
                 const unsigned short* __restrict__ Wvb,
                 const float* __restrict__ bq_, const float* __restrict__ bk_,
                 const float* __restrict__ bv_,
                 unsigned short* __restrict__ Qh, unsigned short* __restrict__ Kh,
                 unsigned short* __restrict__ Vt)
{
    const int z = blockIdx.z;
    const unsigned short* X; const unsigned short* W; const float* bias;
    if (z == 0)      { X = xq; W = Wqb; bias = bq_; }
    else if (z == 1) { X = xk; W = Wkb; bias = bk_; }
    else             { X = xv; W = Wvb; bias = bv_; }

    const int m0 = blockIdx.x * 128;
    const int n0 = blockIdx.y * 128;
    const int tid  = threadIdx.x;
    const int lane = tid & 63, wid = tid >> 6;
    const int wm = (wid >> 1) * 64, wn = (wid & 1) * 64;
    const int l15 = lane & 15, quad = lane >> 4;

    // unified 32 KB: As = SH[0..8191] (2 bufs x 4096), Bs = SH[8192..16383];
    // reused as the 128x128 ushort transpose tile T after the K-loop (z=2).
    __shared__ __align__(16) unsigned short SH[16384];
    unsigned short* As = SH;
    unsigned short* Bs = SH + 8192;

    const int r0 = tid >> 2, cg = tid & 3;
    const unsigned short* gA = X + (size_t)(m0 + r0) * HID + ((cg ^ (r0 & 3)) * 8);
    const unsigned short* gB = W + (size_t)(n0 + r0) * HID + ((cg ^ (r0 & 3)) * 8);

    const int cgsel = (quad ^ (l15 & 3)) * 8;

    f32x4 acc[4][4];
    #pragma unroll
    for (int i = 0; i < 4; ++i)
        #pragma unroll
        for (int j = 0; j < 4; ++j)
            acc[i][j] = f32x4{0.f, 0.f, 0.f, 0.f};

    // prologue: stage k0=0 into buf 0
    glds16(gA, &As[tid * 8]);
    glds16(gA + (size_t)64 * HID, &As[(tid + 256) * 8]);
    glds16(gB, &Bs[tid * 8]);
    glds16(gB + (size_t)64 * HID, &Bs[(tid + 256) * 8]);
    __syncthreads();

    for (int k0 = 0; k0 < HID; k0 += 32) {
        const int cur = ((k0 >> 5) & 1) * 4096;
        if (k0 + 32 < HID) {                       // prefetch next K-step
            const int nb = (((k0 >> 5) & 1) ^ 1) * 4096;
            glds16(gA + k0 + 32, &As[nb + tid * 8]);
            glds16(gA + (size_t)64 * HID + k0 + 32, &As[nb + (tid + 256) * 8]);
            glds16(gB + k0 + 32, &Bs[nb + tid * 8]);
            glds16(gB + (size_t)64 * HID + k0 + 32, &Bs[nb + (tid + 256) * 8]);
        }

        bf16x8 af[4], bfr[4];
        #pragma unroll
        for (int mi = 0; mi < 4; ++mi)
            af[mi] = *(const bf16x8*)&As[cur + (wm + mi * 16 + l15) * 32 + cgsel];
        #pragma unroll
        for (int ni = 0; ni < 4; ++ni)
            bfr[ni] = *(const bf16x8*)&Bs[cur + (wn + ni * 16 + l15) * 32 + cgsel];
        __builtin_amdgcn_s_setprio(1);
        #pragma unroll
        for (int mi = 0; mi < 4; ++mi)
            #pragma unroll
            for (int ni = 0; ni < 4; ++ni)
                acc[mi][ni] = __builtin_amdgcn_mfma_f32_16x16x32_bf16(
                    af[mi], bfr[ni], acc[mi][ni], 0, 0, 0);
        __builtin_amdgcn_s_setprio(0);
        __syncthreads();                           // reads done + prefetch drained
    }

    if (z == 2) {
        // ---- fused V transpose: acc -> T (swizzled) -> Vt[d][s] coalesced --
        #pragma unroll
        for (int mi = 0; mi < 4; ++mi) {
            #pragma unroll
            for (int ni = 0; ni < 4; ++ni) {
                int ncol = wn + ni * 16 + l15;
                float bv = bias[n0 + ncol];
                #pragma unroll
                for (int r = 0; r < 4; ++r) {
                    int row = wm + mi * 16 + quad * 4 + r;
                    SH[row * 128 + (((ncol >> 3) ^ (row & 15)) * 8) + (ncol & 7)] =
                        f32_bf16(acc[mi][ni][r] + bv);
                }
            }
        }
        __syncthreads();
        const int bb = m0 >> 11, sg0 = m0 & 2047;
        #pragma unroll
        for (int jj = 0; jj < 8; ++jj) {
            int idx = tid + jj * 256;
            int colr = idx >> 4, ch = idx & 15;
            int n = n0 + colr, hh = n >> 6, d = n & 63;
            unsigned short v8[8];
            #pragma unroll
            for (int e = 0; e < 8; ++e) {
                int s = ch * 8 + e;
                v8[e] = SH[s * 128 + (((colr >> 3) ^ (s & 15)) * 8) + (colr & 7)];
            }
            uint4 ov;
            ov.x = (unsigned)v8[0] | ((unsigned)v8[1] << 16);
            ov.y = (unsigned)v8[2] | ((unsigned)v8[3] << 16);
            ov.z = (unsigned)v8[4] | ((unsigned)v8[5] << 16);
            ov.w = (unsigned)v8[6] | ((unsigned)v8[7] << 16);
            *(uint4*)(Vt + (((size_t)(bb * NHEAD + hh) * DKK + d) * SEQ + sg0 + ch * 8)) = ov;
        }
        return;
    }

    const float QSCALE = 0.18033688f;   // 0.125 * log2(e)
    #pragma unroll
    for (int mi = 0; mi < 4; ++mi) {
        #pragma unroll
        for (int ni = 0; ni < 4; ++ni) {
            int n = n0 + wn + ni * 16 + l15;
            float bv = bias[n];
            int hh = n >> 6, d = n & 63;
            #pragma unroll
            for (int r = 0; r < 4; ++r) {
                int m = m0 + wm + mi * 16 + quad * 4 + r;
                int bb = m >> 11, s = m & 2047;
                float val = acc[mi][ni][r] + bv;
                if (z == 0)
                    Qh[((size_t)(bb * NHEAD + hh) * SEQ + s) * DKK + d] = f32_bf16(val * QSCALE);
                else
                    Kh[((size_t)(bb * NHEAD + hh) * SEQ + s) * DKK + d] = f32_bf16(val);
            }
        }
    }
}

// ---------------------------------------------------------------------------
// Kernel 2: flash attention, R9 geometry (QBLK=64, 4 waves, 1024 blocks, XCD
// remap, counted-vmcnt pipeline) with P kept IN REGISTERS:
//   swapped-QK^T leaves P in C-layout (lane(quad,q) holds P[k=16ni+4quad+r][q]);
//   the PV A-fragment (lane(qd,q) needs P[q][k=32kc+8qd+e]) is built via
//   v_permlane32_swap_b32 (half exchange) + ds_swizzle 0x401F (lane^16) +
//   cndmask on (lane&16).  Derivation: dest word m of pa[kc] = packed pair
//   from source quad (2*qd + (m>=2)) & 3, fragment ni = 2kc + (qd>>1).
//   Removes 4 ds_write_b64 + 2 ds_read_b128 per wave-tile + all P bank
//   conflicts + the P store->load serialization; frees Ps (LDS 40->32 KB).
// ---------------------------------------------------------------------------
__global__ __launch_bounds__(256, 4)
void attn_kernel(const unsigned short* __restrict__ Qh, const unsigned short* __restrict__ Kh,
                 const unsigned short* __restrict__ Vt,
                 const unsigned long long* __restrict__ Mb,
                 unsigned short* __restrict__ Om)
{
    // XCD-aware decode: flat%8 = XCD (round-robin dispatch, m09/T1)
    const int flat = blockIdx.x;           // 0..1023
    const int xcd  = flat & 7;
    const int rest = flat >> 3;
    const int qt   = rest & 31;
    const int g    = rest >> 5;            // 0..3
    const int hb   = g * 8 + xcd;          // 0..31
    const int h    = hb & 15;
    const int b    = hb >> 4;

    const int tid  = threadIdx.x;
    const int lane = tid & 63, w = tid >> 6;
    const int l15 = lane & 15, quad = lane >> 4;
    const int q0 = qt * 64;

    const size_t hoff = (size_t)(b * NHEAD + h) * SEQ * DKK;
    const unsigned short* Qp = Qh + hoff;
    const unsigned short* Kp = Kh + hoff;
    const unsigned short* Vp = Vt + hoff;   // [d][s]

    __shared__ __align__(16) unsigned short Ks[2][64 * 64];   // 16 KB
    __shared__ __align__(16) unsigned short Vs[2][64 * 64];   // 16 KB

    const int sr0 = tid >> 3, ss0 = tid & 7;
    const int sr1 = sr0 + 32;
    const unsigned short* Kg0 = Kp + sr0 * DKK + ((ss0 ^ (sr0 & 7)) * 8);
    const unsigned short* Kg1 = Kp + sr1 * DKK + ((ss0 ^ (sr1 & 7)) * 8);
    const unsigned short* Vg0 = Vp + (size_t)sr0 * SEQ + ((ss0 ^ (sr0 & 7)) * 8);
    const unsigned short* Vg1 = Vp + (size_t)sr1 * SEQ + ((ss0 ^ (sr1 & 7)) * 8);

    const int swz0 = ((0 * 4 + quad) ^ (l15 & 7)) * 8;
    const int swz1 = ((1 * 4 + quad) ^ (l15 & 7)) * 8;

    const bool hi16 = (lane & 16) != 0;    // quads 1,3

    // prologue: issue tile 0 (4 DMA); Q frags + mask word ride the same queue
    glds16(Kg0, &Ks[0][tid * 8]);
    glds16(Kg1, &Ks[0][2048 + tid * 8]);
    glds16(Vg0, &Vs[0][tid * 8]);
    glds16(Vg1, &Vs[0][2048 + tid * 8]);

    bf16x8 qf[2];
    #pragma unroll
    for (int kc = 0; kc < 2; ++kc)
        qf[kc] = *(const bf16x8*)(Qp + (size_t)(q0 + w * 16 + l15) * DKK + kc * 32 + quad * 8);

    bf16x8 onesf;
    #pragma unroll
    for (int i = 0; i < 8; ++i) onesf[i] = (short)0x3F80;

    f32x4 o_acc[4];
    f32x4 l_acc = f32x4{0.f, 0.f, 0.f, 0.f};
    #pragma unroll
    for (int nd = 0; nd < 4; ++nd) o_acc[nd] = f32x4{0.f, 0.f, 0.f, 0.f};

    const unsigned long long* Mrow =
        Mb + ((size_t)b * SEQ + q0 + w * 16 + l15) * (SEQ / 64);
    unsigned long long mw_cur = Mrow[0];

    for (int kt = 0; kt < SEQ / 64; ++kt) {
        const int cur = kt & 1;
        unsigned long long mw_nxt = 0ull;

        // --- A: issue next batch (exactly 5 vm ops when taken) ------------
        if (kt < SEQ / 64 - 1) {
            const int nb = cur ^ 1;
            glds16(Kg0 + (kt + 1) * 64 * DKK, &Ks[nb][tid * 8]);
            glds16(Kg1 + (kt + 1) * 64 * DKK, &Ks[nb][2048 + tid * 8]);
            glds16(Vg0 + (kt + 1) * 64,       &Vs[nb][tid * 8]);
            glds16(Vg1 + (kt + 1) * 64,       &Vs[nb][2048 + tid * 8]);
            mw_nxt = Mrow[kt + 1];
            // --- B: wait only batch kt (all but the 5 newest), then join --
            asm volatile("s_waitcnt vmcnt(5)" ::: "memory");
        } else {
            asm volatile("s_waitcnt vmcnt(0)" ::: "memory");
        }
        __builtin_amdgcn_s_barrier();          // batch kt resident for ALL waves
        __builtin_amdgcn_sched_barrier(0);     // keep C below the barrier

        // --- C: compute on tile kt ----------------------------------------
        const unsigned long long mwq = mw_cur >> (quad * 4);

        f32x4 st[4];
        #pragma unroll
        for (int ni = 0; ni < 4; ++ni) st[ni] = f32x4{0.f, 0.f, 0.f, 0.f};
        {
            bf16x8 kb[4];
            #pragma unroll
            for (int ni = 0; ni < 4; ++ni)
                kb[ni] = *(const bf16x8*)&Ks[cur][(ni * 16 + l15) * 64 + swz0];
            __builtin_amdgcn_s_setprio(1);
            #pragma unroll
            for (int ni = 0; ni < 4; ++ni)
                st[ni] = __builtin_amdgcn_mfma_f32_16x16x32_bf16(kb[ni], qf[0], st[ni], 0, 0, 0);
            __builtin_amdgcn_s_setprio(0);
            #pragma unroll
            for (int ni = 0; ni < 4; ++ni)
                kb[ni] = *(const bf16x8*)&Ks[cur][(ni * 16 + l15) * 64 + swz1];
            __builtin_amdgcn_s_setprio(1);
            #pragma unroll
            for (int ni = 0; ni < 4; ++ni)
                st[ni] = __builtin_amdgcn_mfma_f32_16x16x32_bf16(kb[ni], qf[1], st[ni], 0, 0, 0);
            __builtin_amdgcn_s_setprio(0);
        }

        // masked exp -> packed bf16 pairs, all in registers
        unsigned int Wp[4][2];
        #pragma unroll
        for (int ni = 0; ni < 4; ++ni) {
            const unsigned int b4 = (unsigned int)(mwq >> (ni * 16)) & 0xFu;
            float p0 = (b4 & 1u) ? fast_exp2(st[ni][0]) : 1.0f;
            float p1 = (b4 & 2u) ? fast_exp2(st[ni][1]) : 1.0f;
            float p2 = (b4 & 4u) ? fast_exp2(st[ni][2]) : 1.0f;
            float p3 = (b4 & 8u) ? fast_exp2(st[ni][3]) : 1.0f;
            Wp[ni][0] = cvt_pk_bf16(p0, p1);
            Wp[ni][1] = cvt_pk_bf16(p2, p3);
        }

        // redistribute C-layout P -> A-fragment pa[kc] (registers only + swizzle)
        bf16x8 paf[2];
        #pragma unroll
        for (int kc = 0; kc < 2; ++kc) {
            unsigned int a0 = Wp[2 * kc][0], b0 = Wp[2 * kc + 1][0];
            plane32_swap(a0, b0);              // a0=[lo|lo], b0=[hi|hi]
            unsigned int xa0 = swz16(a0), xb0 = swz16(b0);
            unsigned int w0 = hi16 ? xb0 : a0; // quads 0,2 <- a0 ; 1,3 <- b0^16
            unsigned int w2 = hi16 ? b0 : xa0; // quads 1,3 <- b0 ; 0,2 <- a0^16

            unsigned int a1 = Wp[2 * kc][1], b1 = Wp[2 * kc + 1][1];
            plane32_swap(a1, b1);
            unsigned int xa1 = swz16(a1), xb1 = swz16(b1);
            unsigned int w1 = hi16 ? xb1 : a1;
            unsigned int w3 = hi16 ? b1 : xa1;

            uint4 uw; uw.x = w0; uw.y = w1; uw.z = w2; uw.w = w3;
            paf[kc] = __builtin_bit_cast(bf16x8, uw);
        }

        // PV + row-sum (ones trick), P from registers
        {
            bf16x8 vb[4];
            #pragma unroll
            for (int nd = 0; nd < 4; ++nd)
                vb[nd] = *(const bf16x8*)&Vs[cur][(nd * 16 + l15) * 64 + swz0];
            __builtin_amdgcn_s_setprio(1);
            l_acc = __builtin_amdgcn_mfma_f32_16x16x32_bf16(paf[0], onesf, l_acc, 0, 0, 0);
            #pragma unroll
            for (int nd = 0; nd < 4; ++nd)
                o_acc[nd] = __builtin_amdgcn_mfma_f32_16x16x32_bf16(paf[0], vb[nd], o_acc[nd], 0, 0, 0);
            __builtin_amdgcn_s_setprio(0);

            #pragma unroll
            for (int nd = 0; nd < 4; ++nd)
                vb[nd] = *(const bf16x8*)&Vs[cur][(nd * 16 + l15) * 64 + swz1];
            __builtin_amdgcn_s_setprio(1);
            l_acc = __builtin_amdgcn_mfma_f32_16x16x32_bf16(paf[1], onesf, l_acc, 0, 0, 0);
            #pragma unroll
            for (int nd = 0; nd < 4; ++nd)
                o_acc[nd] = __builtin_amdgcn_mfma_f32_16x16x32_bf16(paf[1], vb[nd], o_acc[nd], 0, 0, 0);
            __builtin_amdgcn_s_setprio(0);
        }

        mw_cur = mw_nxt;

        // --- D: all reads of buf[cur] done before next A overwrites it ----
        __builtin_amdgcn_s_barrier();
        __builtin_amdgcn_sched_barrier(0);     // pin next A below this barrier
    }

    #pragma unroll
    for (int r = 0; r < 4; ++r) {
        float rinv = 1.0f / l_acc[r];
        int row = q0 + w * 16 + quad * 4 + r;
        #pragma unroll
        for (int nd = 0; nd < 4; ++nd)
            Om[((size_t)b * SEQ + row) * HID + h * DKK + nd * 16 + l15] =
                f32_bf16(o_acc[nd][r] * rinv);
    }
}

// ---------------------------------------------------------------------------
// Kernel 3: out = Om @ Wo^T + bo (fp32 out).  128x64 tiles, R4-verified
// double-buffer single-barrier K-loop.
// ---------------------------------------------------------------------------
__global__ __launch_bounds__(256, 2)
void outproj_kernel(const unsigned short* __restrict__ Om, const unsigned short* __restrict__ Wob,
                    const float* __restrict__ bo_, float* __restrict__ out)
{
    const int m0 = blockIdx.x * 128;
    const int n0 = blockIdx.y * 64;
    const int tid  = threadIdx.x;
    const int lane = tid & 63, wid = tid >> 6;
    const int wm = (wid >> 1) * 64, wn = (wid & 1) * 32;
    const int l15 = lane & 15, quad = lane >> 4;

    __shared__ __align__(16) unsigned short As[2][128 * 32];   // 2 x 8 KB
    __shared__ __align__(16) unsigned short Bs[2][64 * 32];    // 2 x 4 KB

    const int r0 = tid >> 2, cg = tid & 3;
    const unsigned short* gA = Om + (size_t)(m0 + r0) * HID + ((cg ^ (r0 & 3)) * 8);
    const unsigned short* gB = Wob + (size_t)(n0 + r0) * HID + ((cg ^ (r0 & 3)) * 8);
    const int cgsel = (quad ^ (l15 & 3)) * 8;

    f32x4 acc[4][2];
    #pragma unroll
    for (int i = 0; i < 4; ++i)
        #pragma unroll
        for (int j = 0; j < 2; ++j)
            acc[i][j] = f32x4{0.f, 0.f, 0.f, 0.f};

    // prologue: stage k0=0
    glds16(gA, &As[0][tid * 8]);
    glds16(gA + (size_t)64 * HID, &As[0][(tid + 256) * 8]);
    glds16(gB, &Bs[0][tid * 8]);
    __syncthreads();

    for (int k0 = 0; k0 < HID; k0 += 32) {
        const int cur = (k0 >> 5) & 1;
        if (k0 + 32 < HID) {
            const int nb = cur ^ 1;
            glds16(gA + k0 + 32, &As[nb][tid * 8]);
            glds16(gA + (size_t)64 * HID + k0 + 32, &As[nb][(tid + 256) * 8]);
            glds16(gB + k0 + 32, &Bs[nb][tid * 8]);
        }

        bf16x8 af[4], bfr[2];
        #pragma unroll
        for (int mi = 0; mi < 4; ++mi)
            af[mi] = *(const bf16x8*)&As[cur][(wm + mi * 16 + l15) * 32 + cgsel];
        #pragma unroll
        for (int ni = 0; ni < 2; ++ni)
            bfr[ni] = *(const bf16x8*)&Bs[cur][(wn + ni * 16 + l15) * 32 + cgsel];
        __builtin_amdgcn_s_setprio(1);
        #pragma unroll
        for (int mi = 0; mi < 4; ++mi)
            #pragma unroll
            for (int ni = 0; ni < 2; ++ni)
                acc[mi][ni] = __builtin_amdgcn_mfma_f32_16x16x32_bf16(
                    af[mi], bfr[ni], acc[mi][ni], 0, 0, 0);
        __builtin_amdgcn_s_setprio(0);
        __syncthreads();
    }

    #pragma unroll
    for (int mi = 0; mi < 4; ++mi) {
        #pragma unroll
        for (int ni = 0; ni < 2; ++ni) {
            int n = n0 + wn + ni * 16 + l15;
            float bv = bo_[n];
            #pragma unroll
            for (int r = 0; r < 4; ++r) {
                int m = m0 + wm + mi * 16 + quad * 4 + r;
                out[(size_t)m * HID + n] = acc[mi][ni][r] + bv;
            }
        }
    }
}

// ---------------------------------------------------------------------------
extern "C" void kernel_launch(void* const* d_in, const int* in_sizes, int n_in,
                              void* d_out, int out_size, void* d_ws, size_t ws_size,
                              hipStream_t stream) {
    const float* q    = (const float*)d_in[0];
    const float* k    = (const float*)d_in[1];
    const float* v    = (const float*)d_in[2];
    const int*   mask = (const int*)  d_in[3];
    const float* Wq   = (const float*)d_in[4];
    const float* bq   = (const float*)d_in[5];
    const float* Wk   = (const float*)d_in[6];
    const float* bk   = (const float*)d_in[7];
    const float* Wv   = (const float*)d_in[8];
    const float* bv   = (const float*)d_in[9];
    const float* Wo   = (const float*)d_in[10];
    const float* bo   = (const float*)d_in[11];
    float* out = (float*)d_out;

    // workspace layout (bf16 element offsets):
    unsigned short* ws  = (unsigned short*)d_ws;
    unsigned short* qb  = ws;                  // 4194304 elems (B*S*H)
    unsigned short* kbx = ws + 4194304;
    unsigned short* vbx = ws + 8388608;
    unsigned short* Wqb = ws + 12582912;       // 1048576 elems each
    unsigned short* Wkb = ws + 13631488;
    unsigned short* Wvb = ws + 14680064;
    unsigned short* Wob = ws + 15728640;
    unsigned short* Qh  = ws + 16777216;
    unsigned short* Kh  = ws + 20971520;
    unsigned short* Vt  = ws + 25165824;
    unsigned short* Om  = ws;                  // alias qb (dead after proj)
    unsigned long long* Mb = (unsigned long long*)(ws + 29360128);  // 1 MB

    prep_kernel<<<dim3(16896), 256, 0, stream>>>(q, k, v, Wq, Wk, Wv, Wo, mask, ws, Mb);

    proj_kernel<<<dim3(32, 8, 3), 256, 0, stream>>>(qb, kbx, vbx, Wqb, Wkb, Wvb,
                                                    bq, bk, bv, Qh, Kh, Vt);
    attn_kernel<<<dim3(1024), 256, 0, stream>>>(Qh, Kh, Vt, Mb, Om);
    outproj_kernel<<<dim3(32, 16), 256, 0, stream>>>(Om, Wob, bo, out);
}